// Round 19
// baseline (239.295 us; speedup 1.0000x reference)
//
#include <hip/hip_runtime.h>

#define L_SEQ 4096
#define D_DIM 512
#define H_DIM 512
#define P_PAD 16
#define LB 4
#define NR (LB + 2 * P_PAD)   // 36 x-rows per gather block
#define LOG2E2 2.885390081777927f   // 2*log2(e)
#define LOG2E  1.4426950408889634f

typedef __bf16 bf16x8 __attribute__((ext_vector_type(8)));
typedef float  f32x4  __attribute__((ext_vector_type(4)));
typedef unsigned short u16x8 __attribute__((ext_vector_type(8)));

extern "C" __device__ float __ocml_native_exp2_f32(float);

__device__ __forceinline__ float exp2_fast(float x) {
#if __has_builtin(__builtin_amdgcn_exp2f)
    return __builtin_amdgcn_exp2f(x);
#else
    return __ocml_native_exp2_f32(x);   // single v_exp_f32
#endif
}

__device__ __forceinline__ ushort f2bf(float f) {
    unsigned u = __float_as_uint(f);
    return (ushort)((u + 0x7FFFu + ((u >> 16) & 1u)) >> 16);   // RNE
}
__device__ __forceinline__ float bf2f(ushort s) {
    return __uint_as_float((unsigned)s << 16);
}

// wave-uniform broadcast of lane `sl` (compile-time) -> SGPR value
__device__ __forceinline__ float readlane_f(float v, int sl) {
    return __uint_as_float(__builtin_amdgcn_readlane(__float_as_uint(v), sl));
}

// ---- GEMM with fused f32->bf16 convert (reg-staged, swizzled ds_write) ----
// E[m][n] = exp2(LOG2E2 * sum_k x[m][k]*W[n][k]); z&1 selects Ww->Ewb / Wu->Eub.
// z>>1 is a diagnostic rep index (identical idempotent work; body unperturbed).
__global__ __launch_bounds__(256, 2) void dual_gemm_mfma(
    const float* __restrict__ x, const float* __restrict__ Ww,
    const float* __restrict__ Wu, ushort* __restrict__ Ewb, ushort* __restrict__ Eub)
{
    const float* Bw = (blockIdx.z & 1) ? Wu : Ww;
    ushort*      out = (blockIdx.z & 1) ? Eub : Ewb;
    const int m0 = blockIdx.x * 128;
    const int n0 = blockIdx.y * 64;

    __shared__ __align__(16) ushort As[2][128 * 64];  // 2 x 16KB
    __shared__ __align__(16) ushort Bs[2][64 * 64];   // 2 x  8KB

    const int tid  = threadIdx.x;
    const int wv   = tid >> 6;
    const int lane = tid & 63;
    const int wm   = (wv >> 1) * 64;
    const int wn   = (wv & 1) * 32;
    const int lr   = lane & 15;
    const int lg   = lane >> 4;
    const int rx   = lr & 7;   // read-side swizzle key

    f32x4 acc[4][2] = {};

    auto stage = [&](int t, int buf) {
        const int k0 = t * 64;
        #pragma unroll
        for (int i = 0; i < 4; ++i) {
            int c = i * 256 + tid, row = c >> 3, q = c & 7;
            const float* s = x + (size_t)(m0 + row) * D_DIM + k0 + q * 8;
            float4 f0 = *(const float4*)s;
            float4 f1 = *(const float4*)(s + 4);
            u16x8 hv;
            hv[0] = f2bf(f0.x); hv[1] = f2bf(f0.y); hv[2] = f2bf(f0.z); hv[3] = f2bf(f0.w);
            hv[4] = f2bf(f1.x); hv[5] = f2bf(f1.y); hv[6] = f2bf(f1.z); hv[7] = f2bf(f1.w);
            *(u16x8*)&As[buf][row * 64 + ((q ^ (row & 7)) * 8)] = hv;
        }
        #pragma unroll
        for (int i = 0; i < 2; ++i) {
            int c = i * 256 + tid, row = c >> 3, q = c & 7;
            const float* s = Bw + (size_t)(n0 + row) * D_DIM + k0 + q * 8;
            float4 f0 = *(const float4*)s;
            float4 f1 = *(const float4*)(s + 4);
            u16x8 hv;
            hv[0] = f2bf(f0.x); hv[1] = f2bf(f0.y); hv[2] = f2bf(f0.z); hv[3] = f2bf(f0.w);
            hv[4] = f2bf(f1.x); hv[5] = f2bf(f1.y); hv[6] = f2bf(f1.z); hv[7] = f2bf(f1.w);
            *(u16x8*)&Bs[buf][row * 64 + ((q ^ (row & 7)) * 8)] = hv;
        }
    };

    auto compute = [&](int buf) {
        #pragma unroll
        for (int kk = 0; kk < 2; ++kk) {
            bf16x8 a[4], b[2];
            #pragma unroll
            for (int mi = 0; mi < 4; ++mi)
                a[mi] = *(const bf16x8*)&As[buf][(wm + mi * 16 + lr) * 64 +
                                                 (((kk * 4 + lg) ^ rx) * 8)];
            #pragma unroll
            for (int ni = 0; ni < 2; ++ni)
                b[ni] = *(const bf16x8*)&Bs[buf][(wn + ni * 16 + lr) * 64 +
                                                 (((kk * 4 + lg) ^ rx) * 8)];
            #pragma unroll
            for (int mi = 0; mi < 4; ++mi)
                #pragma unroll
                for (int ni = 0; ni < 2; ++ni)
                    acc[mi][ni] = __builtin_amdgcn_mfma_f32_16x16x32_bf16(
                        a[mi], b[ni], acc[mi][ni], 0, 0, 0);
        }
    };

    stage(0, 0);
    __syncthreads();
    #pragma unroll
    for (int t = 0; t < 7; ++t) {
        stage(t + 1, (t + 1) & 1);
        compute(t & 1);
        __syncthreads();
    }
    compute(1);

    // D layout: col = lane&15, row = (lane>>4)*4 + r
    #pragma unroll
    for (int mi = 0; mi < 4; ++mi)
        #pragma unroll
        for (int ni = 0; ni < 2; ++ni)
            #pragma unroll
            for (int r = 0; r < 4; ++r)
                out[(size_t)(m0 + wm + mi * 16 + lg * 4 + r) * H_DIM + n0 + wn + ni * 16 + lr] =
                    f2bf(exp2_fast(LOG2E2 * acc[mi][ni][r]));
}

// ---- fused scores + softmax + gather (R16 structure; blockIdx.y = rep) ----
template<bool EDGE>
__device__ __forceinline__ void fused_body(
    const ushort* __restrict__ Ewb, const ushort* __restrict__ Eub,
    const float* __restrict__ Wv, const float* __restrict__ x,
    float* __restrict__ g, int l0,
    float sc_lds[LB][32], float at_lds[LB][32])
{
    const int tid  = threadIdx.x;
    const int wv   = tid >> 6;
    const int lane = tid & 63;
    const int li   = wv >> 1;
    const int half = wv & 1;
    const int l    = l0 + li;
    const int col  = tid;

    // ---- phase 1: scores ----
    float ewr[8], wvn[8];
    {
        u16x8 ew8 = *(const u16x8*)&Ewb[(size_t)l * H_DIM + lane * 8];
        const f32x4* wvp = (const f32x4*)&Wv[lane * 8];
        f32x4 v0 = wvp[0], v1 = wvp[1];
        #pragma unroll
        for (int e = 0; e < 8; ++e) ewr[e] = bf2f(ew8[e]);
        #pragma unroll
        for (int e = 0; e < 4; ++e) { wvn[e] = -2.0f * v0[e]; wvn[e + 4] = -2.0f * v1[e]; }
    }

    float aoob = 0.0f;
    if (EDGE && (l < P_PAD || l >= L_SEQ - P_PAD)) {
        #pragma unroll
        for (int e = 0; e < 8; ++e)
            aoob = __builtin_fmaf(wvn[e], __builtin_amdgcn_rcpf(ewr[e] + 1.0f), aoob);
    }

    const ushort* base = Eub + (size_t)l * H_DIM + lane * 8;
    #pragma unroll
    for (int q = 0; q < 4; ++q) {
        u16x8 u[4];
        int valid[4];
        #pragma unroll
        for (int wi = 0; wi < 4; ++wi) {
            const int w = half * 16 + q * 4 + wi;
            const int j = (w < P_PAD) ? (w - P_PAD) : (w - P_PAD + 1);
            if (EDGE) {
                int n = l + j;
                valid[wi] = ((unsigned)n < (unsigned)L_SEQ);
                n = min(max(n, 0), L_SEQ - 1);
                u[wi] = *(const u16x8*)&Eub[(size_t)n * H_DIM + lane * 8];
            } else {
                u[wi] = *(const u16x8*)(base + j * H_DIM);
            }
        }
        float a4[4];
        #pragma unroll
        for (int wi = 0; wi < 4; ++wi) {
            float a = 0.0f;
            #pragma unroll
            for (int e = 0; e < 8; ++e) {
                float eu = bf2f(u[wi][e]);
                float qq = __builtin_fmaf(ewr[e], eu, 1.0f);
                a = __builtin_fmaf(wvn[e], __builtin_amdgcn_rcpf(qq), a);
            }
            if (EDGE) a = valid[wi] ? a : aoob;
            a4[wi] = a;
        }
        // pack 4 accs -> lane&3 slots (3 shfl), then 4 butterflies
        const bool b0 = lane & 1, b1 = lane & 2;
        float s01 = b0 ? a4[0] : a4[1];
        float r01 = __shfl_xor(s01, 1);
        float c0  = (b0 ? a4[1] : a4[0]) + r01;
        float s23 = b0 ? a4[2] : a4[3];
        float r23 = __shfl_xor(s23, 1);
        float c1  = (b0 ? a4[3] : a4[2]) + r23;
        float s2  = b1 ? c0 : c1;
        float r2  = __shfl_xor(s2, 2);
        float c   = (b1 ? c1 : c0) + r2;
        c += __shfl_xor(c, 4);
        c += __shfl_xor(c, 8);
        c += __shfl_xor(c, 16);
        c += __shfl_xor(c, 32);
        if (lane < 4) sc_lds[li][half * 16 + q * 4 + lane] = c;
    }

    // issue xv loads after phase-1 register peak, before the barrier
    float xv[NR];
    #pragma unroll
    for (int t = 0; t < NR; ++t) {
        int n = l0 - P_PAD + t;
        if (EDGE) n = min(max(n, 0), L_SEQ - 1);
        xv[t] = x[(size_t)n * D_DIM + col];
    }
    __syncthreads();

    // ---- phase 2: softmax (threads 0..127, 32-wide groups) ----
    if (tid < LB * 32) {
        const int ll = tid >> 5, w = tid & 31;
        float s0 = sc_lds[ll][w];
        float m = s0;
        #pragma unroll
        for (int off = 16; off; off >>= 1) m = fmaxf(m, __shfl_xor(m, off, 32));
        float e = exp2_fast((s0 - m) * LOG2E);
        float sum = e;
        #pragma unroll
        for (int off = 16; off; off >>= 1) sum += __shfl_xor(sum, off, 32);
        at_lds[ll][w] = e * __builtin_amdgcn_rcpf(sum);
    }
    __syncthreads();

    // ---- phase 3: gather; weights via LDS float2/lane + v_readlane (SGPR) ----
    float2 aw2 = ((const float2*)at_lds)[lane];   // 128 weights, 2/lane

    #pragma unroll
    for (int li2 = 0; li2 < LB; ++li2) {
        float a = 0.0f;
        #pragma unroll
        for (int w = 0; w < 32; ++w) {
            const int j = (w < P_PAD) ? (w - P_PAD) : (w - P_PAD + 1);
            const int t = j + P_PAD + li2;          // 0..35, compile-time
            const int k = li2 * 32 + w;
            float aw = readlane_f((k & 1) ? aw2.y : aw2.x, k >> 1);
            if (EDGE) {
                const int n = l0 + li2 + j;         // uniform -> scalar select
                if (n < 0 || n >= L_SEQ) aw = 0.0f;
            }
            a = __builtin_fmaf(aw, xv[t], a);
        }
        g[(size_t)(l0 + li2) * D_DIM + col] = a;
    }
}

__global__ __launch_bounds__(512, 4) void scores_gather_kernel(
    const ushort* __restrict__ Ewb, const ushort* __restrict__ Eub,
    const float* __restrict__ Wv, const float* __restrict__ x,
    float* __restrict__ g)
{
    // XCD swizzle: grid.x=1024 -> 128 consecutive blocks per XCD.
    // blockIdx.y = diagnostic rep (identical idempotent work).
    const int bid = (blockIdx.x & 7) * 128 + (blockIdx.x >> 3);
    const int l0  = bid * LB;

    __shared__ __align__(16) float sc_lds[LB][32];
    __shared__ __align__(16) float at_lds[LB][32];

    if (l0 >= P_PAD && l0 + LB + P_PAD <= L_SEQ)
        fused_body<false>(Ewb, Eub, Wv, x, g, l0, sc_lds, at_lds);
    else
        fused_body<true>(Ewb, Eub, Wv, x, g, l0, sc_lds, at_lds);
}

extern "C" void kernel_launch(void* const* d_in, const int* in_sizes, int n_in,
                              void* d_out, int out_size, void* d_ws, size_t ws_size,
                              hipStream_t stream) {
    const float* x  = (const float*)d_in[0];
    const float* Ww = (const float*)d_in[1];
    const float* Wu = (const float*)d_in[2];
    const float* Wv = (const float*)d_in[3];
    float* g = (float*)d_out;

    ushort* Ewb = (ushort*)d_ws;                // 4 MB bf16 [L][H]
    ushort* Eub = Ewb + (size_t)L_SEQ * H_DIM;  // 4 MB bf16 [L][H]

    // Diagnostic round: grid-level x10 repetition (identical idempotent work per
    // rep) so each dispatch's dur exceeds the 40us poison fills and surfaces in
    // rocprof top-5 with UNPERTURBED per-kernel counters. True dur = dur/10.
    dual_gemm_mfma<<<dim3(L_SEQ / 128, H_DIM / 64, 20), 256, 0, stream>>>(x, Ww, Wu, Ewb, Eub);
    scores_gather_kernel<<<dim3(L_SEQ / LB, 10), 512, 0, stream>>>(Ewb, Eub, Wv, x, g);
}

// Round 20
// 37.035 us; speedup vs baseline: 6.4613x; 6.4613x over previous
//
#include <hip/hip_runtime.h>

#define L_SEQ 4096
#define D_DIM 512
#define H_DIM 512
#define P_PAD 16
#define LB 4
#define NR (LB + 2 * P_PAD)   // 36 x-rows per gather block
#define LOG2E2 2.885390081777927f   // 2*log2(e)
#define LOG2E  1.4426950408889634f

typedef __bf16 bf16x8 __attribute__((ext_vector_type(8)));
typedef float  f32x4  __attribute__((ext_vector_type(4)));
typedef unsigned short u16x8 __attribute__((ext_vector_type(8)));

extern "C" __device__ float __ocml_native_exp2_f32(float);

__device__ __forceinline__ float exp2_fast(float x) {
#if __has_builtin(__builtin_amdgcn_exp2f)
    return __builtin_amdgcn_exp2f(x);
#else
    return __ocml_native_exp2_f32(x);   // single v_exp_f32
#endif
}

__device__ __forceinline__ ushort f2bf(float f) {
    unsigned u = __float_as_uint(f);
    return (ushort)((u + 0x7FFFu + ((u >> 16) & 1u)) >> 16);   // RNE
}
__device__ __forceinline__ float bf2f(ushort s) {
    return __uint_as_float((unsigned)s << 16);
}

// wave-uniform broadcast of lane `sl` (compile-time) -> SGPR value
__device__ __forceinline__ float readlane_f(float v, int sl) {
    return __uint_as_float(__builtin_amdgcn_readlane(__float_as_uint(v), sl));
}

// ---- GEMM with fused f32->bf16 convert (reg-staged, swizzled ds_write) ----
// E[m][n] = exp2(LOG2E2 * sum_k x[m][k]*W[n][k]); z selects Ww->Ewb / Wu->Eub.
__global__ __launch_bounds__(256, 2) void dual_gemm_mfma(
    const float* __restrict__ x, const float* __restrict__ Ww,
    const float* __restrict__ Wu, ushort* __restrict__ Ewb, ushort* __restrict__ Eub)
{
    const float* Bw = blockIdx.z ? Wu : Ww;
    ushort*      out = blockIdx.z ? Eub : Ewb;
    const int m0 = blockIdx.x * 128;
    const int n0 = blockIdx.y * 64;

    __shared__ __align__(16) ushort As[2][128 * 64];  // 2 x 16KB
    __shared__ __align__(16) ushort Bs[2][64 * 64];   // 2 x  8KB

    const int tid  = threadIdx.x;
    const int wv   = tid >> 6;
    const int lane = tid & 63;
    const int wm   = (wv >> 1) * 64;
    const int wn   = (wv & 1) * 32;
    const int lr   = lane & 15;
    const int lg   = lane >> 4;
    const int rx   = lr & 7;   // read-side swizzle key

    f32x4 acc[4][2] = {};

    auto stage = [&](int t, int buf) {
        const int k0 = t * 64;
        #pragma unroll
        for (int i = 0; i < 4; ++i) {
            int c = i * 256 + tid, row = c >> 3, q = c & 7;
            const float* s = x + (size_t)(m0 + row) * D_DIM + k0 + q * 8;
            float4 f0 = *(const float4*)s;
            float4 f1 = *(const float4*)(s + 4);
            u16x8 hv;
            hv[0] = f2bf(f0.x); hv[1] = f2bf(f0.y); hv[2] = f2bf(f0.z); hv[3] = f2bf(f0.w);
            hv[4] = f2bf(f1.x); hv[5] = f2bf(f1.y); hv[6] = f2bf(f1.z); hv[7] = f2bf(f1.w);
            *(u16x8*)&As[buf][row * 64 + ((q ^ (row & 7)) * 8)] = hv;
        }
        #pragma unroll
        for (int i = 0; i < 2; ++i) {
            int c = i * 256 + tid, row = c >> 3, q = c & 7;
            const float* s = Bw + (size_t)(n0 + row) * D_DIM + k0 + q * 8;
            float4 f0 = *(const float4*)s;
            float4 f1 = *(const float4*)(s + 4);
            u16x8 hv;
            hv[0] = f2bf(f0.x); hv[1] = f2bf(f0.y); hv[2] = f2bf(f0.z); hv[3] = f2bf(f0.w);
            hv[4] = f2bf(f1.x); hv[5] = f2bf(f1.y); hv[6] = f2bf(f1.z); hv[7] = f2bf(f1.w);
            *(u16x8*)&Bs[buf][row * 64 + ((q ^ (row & 7)) * 8)] = hv;
        }
    };

    auto compute = [&](int buf) {
        #pragma unroll
        for (int kk = 0; kk < 2; ++kk) {
            bf16x8 a[4], b[2];
            #pragma unroll
            for (int mi = 0; mi < 4; ++mi)
                a[mi] = *(const bf16x8*)&As[buf][(wm + mi * 16 + lr) * 64 +
                                                 (((kk * 4 + lg) ^ rx) * 8)];
            #pragma unroll
            for (int ni = 0; ni < 2; ++ni)
                b[ni] = *(const bf16x8*)&Bs[buf][(wn + ni * 16 + lr) * 64 +
                                                 (((kk * 4 + lg) ^ rx) * 8)];
            #pragma unroll
            for (int mi = 0; mi < 4; ++mi)
                #pragma unroll
                for (int ni = 0; ni < 2; ++ni)
                    acc[mi][ni] = __builtin_amdgcn_mfma_f32_16x16x32_bf16(
                        a[mi], b[ni], acc[mi][ni], 0, 0, 0);
        }
    };

    stage(0, 0);
    __syncthreads();
    #pragma unroll
    for (int t = 0; t < 7; ++t) {
        stage(t + 1, (t + 1) & 1);
        compute(t & 1);
        __syncthreads();
    }
    compute(1);

    // D layout: col = lane&15, row = (lane>>4)*4 + r
    #pragma unroll
    for (int mi = 0; mi < 4; ++mi)
        #pragma unroll
        for (int ni = 0; ni < 2; ++ni)
            #pragma unroll
            for (int r = 0; r < 4; ++r)
                out[(size_t)(m0 + wm + mi * 16 + lg * 4 + r) * H_DIM + n0 + wn + ni * 16 + lr] =
                    f2bf(exp2_fast(LOG2E2 * acc[mi][ni][r]));
}

// ---- fused scores + softmax + gather; paired-denominator sigmoid dot ----
// Pair trick: wv1*rcp(d1) + wv2*rcp(d2) = (wv1*d2 + wv2*d1) * rcp(d1*d2)
// -> ONE v_rcp (quarter-rate transcendental) per bf16 PAIR instead of two.
template<bool EDGE>
__device__ __forceinline__ void fused_body(
    const ushort* __restrict__ Ewb, const ushort* __restrict__ Eub,
    const float* __restrict__ Wv, const float* __restrict__ x,
    float* __restrict__ g, int l0,
    float sc_lds[LB][32], float at_lds[LB][32])
{
    const int tid  = threadIdx.x;
    const int wv   = tid >> 6;
    const int lane = tid & 63;
    const int li   = wv >> 1;
    const int half = wv & 1;
    const int l    = l0 + li;
    const int col  = tid;

    // ---- phase 1: scores ----
    float ewr[8], wvn[8];
    {
        u16x8 ew8 = *(const u16x8*)&Ewb[(size_t)l * H_DIM + lane * 8];
        const f32x4* wvp = (const f32x4*)&Wv[lane * 8];
        f32x4 v0 = wvp[0], v1 = wvp[1];
        #pragma unroll
        for (int e = 0; e < 8; ++e) ewr[e] = bf2f(ew8[e]);
        #pragma unroll
        for (int e = 0; e < 4; ++e) { wvn[e] = -2.0f * v0[e]; wvn[e + 4] = -2.0f * v1[e]; }
    }

    float aoob = 0.0f;
    if (EDGE && (l < P_PAD || l >= L_SEQ - P_PAD)) {
        #pragma unroll
        for (int e = 0; e < 8; ++e)
            aoob = __builtin_fmaf(wvn[e], __builtin_amdgcn_rcpf(ewr[e] + 1.0f), aoob);
    }

    const ushort* base = Eub + (size_t)l * H_DIM + lane * 8;
    #pragma unroll
    for (int q = 0; q < 4; ++q) {
        uint4 u[4];
        int valid[4];
        #pragma unroll
        for (int wi = 0; wi < 4; ++wi) {
            const int w = half * 16 + q * 4 + wi;
            const int j = (w < P_PAD) ? (w - P_PAD) : (w - P_PAD + 1);
            if (EDGE) {
                int n = l + j;
                valid[wi] = ((unsigned)n < (unsigned)L_SEQ);
                n = min(max(n, 0), L_SEQ - 1);
                u[wi] = *(const uint4*)&Eub[(size_t)n * H_DIM + lane * 8];
            } else {
                u[wi] = *(const uint4*)(base + j * H_DIM);
            }
        }
        float a4[4];
        #pragma unroll
        for (int wi = 0; wi < 4; ++wi) {
            float a = 0.0f;
            #pragma unroll
            for (int p = 0; p < 4; ++p) {
                unsigned uw = ((const unsigned*)&u[wi])[p];   // 2 bf16: lo=2p, hi=2p+1
                float elo = __uint_as_float(uw << 16);
                float ehi = __uint_as_float(uw & 0xffff0000u);
                float dlo = __builtin_fmaf(ewr[2 * p],     elo, 1.0f);
                float dhi = __builtin_fmaf(ewr[2 * p + 1], ehi, 1.0f);
                float num = __builtin_fmaf(wvn[2 * p + 1], dlo, wvn[2 * p] * dhi);
                float den = dlo * dhi;
                a = __builtin_fmaf(num, __builtin_amdgcn_rcpf(den), a);
            }
            if (EDGE) a = valid[wi] ? a : aoob;
            a4[wi] = a;
        }
        // pack 4 accs -> lane&3 slots (3 shfl), then 4 butterflies
        const bool b0 = lane & 1, b1 = lane & 2;
        float s01 = b0 ? a4[0] : a4[1];
        float r01 = __shfl_xor(s01, 1);
        float c0  = (b0 ? a4[1] : a4[0]) + r01;
        float s23 = b0 ? a4[2] : a4[3];
        float r23 = __shfl_xor(s23, 1);
        float c1  = (b0 ? a4[3] : a4[2]) + r23;
        float s2  = b1 ? c0 : c1;
        float r2  = __shfl_xor(s2, 2);
        float c   = (b1 ? c1 : c0) + r2;
        c += __shfl_xor(c, 4);
        c += __shfl_xor(c, 8);
        c += __shfl_xor(c, 16);
        c += __shfl_xor(c, 32);
        if (lane < 4) sc_lds[li][half * 16 + q * 4 + lane] = c;
    }

    // xv loads (compiler schedules; kernel is VALU-bound anyway)
    float xv[NR];
    #pragma unroll
    for (int t = 0; t < NR; ++t) {
        int n = l0 - P_PAD + t;
        if (EDGE) n = min(max(n, 0), L_SEQ - 1);
        xv[t] = x[(size_t)n * D_DIM + col];
    }
    __syncthreads();

    // ---- phase 2: softmax (threads 0..127, 32-wide groups) ----
    if (tid < LB * 32) {
        const int ll = tid >> 5, w = tid & 31;
        float s0 = sc_lds[ll][w];
        float m = s0;
        #pragma unroll
        for (int off = 16; off; off >>= 1) m = fmaxf(m, __shfl_xor(m, off, 32));
        float e = exp2_fast((s0 - m) * LOG2E);
        float sum = e;
        #pragma unroll
        for (int off = 16; off; off >>= 1) sum += __shfl_xor(sum, off, 32);
        at_lds[ll][w] = e * __builtin_amdgcn_rcpf(sum);
    }
    __syncthreads();

    // ---- phase 3: gather; weights via LDS float2/lane + v_readlane (SGPR) ----
    float2 aw2 = ((const float2*)at_lds)[lane];   // 128 weights, 2/lane

    #pragma unroll
    for (int li2 = 0; li2 < LB; ++li2) {
        float a = 0.0f;
        #pragma unroll
        for (int w = 0; w < 32; ++w) {
            const int j = (w < P_PAD) ? (w - P_PAD) : (w - P_PAD + 1);
            const int t = j + P_PAD + li2;          // 0..35, compile-time
            const int k = li2 * 32 + w;
            float aw = readlane_f((k & 1) ? aw2.y : aw2.x, k >> 1);
            if (EDGE) {
                const int n = l0 + li2 + j;         // uniform -> scalar select
                if (n < 0 || n >= L_SEQ) aw = 0.0f;
            }
            a = __builtin_fmaf(aw, xv[t], a);
        }
        g[(size_t)(l0 + li2) * D_DIM + col] = a;
    }
}

__global__ __launch_bounds__(512, 4) void scores_gather_kernel(
    const ushort* __restrict__ Ewb, const ushort* __restrict__ Eub,
    const float* __restrict__ Wv, const float* __restrict__ x,
    float* __restrict__ g)
{
    // XCD swizzle: grid=1024 -> 128 consecutive blocks per XCD
    const int bid = (blockIdx.x & 7) * 128 + (blockIdx.x >> 3);
    const int l0  = bid * LB;

    __shared__ __align__(16) float sc_lds[LB][32];
    __shared__ __align__(16) float at_lds[LB][32];

    if (l0 >= P_PAD && l0 + LB + P_PAD <= L_SEQ)
        fused_body<false>(Ewb, Eub, Wv, x, g, l0, sc_lds, at_lds);
    else
        fused_body<true>(Ewb, Eub, Wv, x, g, l0, sc_lds, at_lds);
}

extern "C" void kernel_launch(void* const* d_in, const int* in_sizes, int n_in,
                              void* d_out, int out_size, void* d_ws, size_t ws_size,
                              hipStream_t stream) {
    const float* x  = (const float*)d_in[0];
    const float* Ww = (const float*)d_in[1];
    const float* Wu = (const float*)d_in[2];
    const float* Wv = (const float*)d_in[3];
    float* g = (float*)d_out;

    ushort* Ewb = (ushort*)d_ws;                // 4 MB bf16 [L][H]
    ushort* Eub = Ewb + (size_t)L_SEQ * H_DIM;  // 4 MB bf16 [L][H]

    dual_gemm_mfma<<<dim3(L_SEQ / 128, H_DIM / 64, 2), 256, 0, stream>>>(x, Ww, Wu, Ewb, Eub);
    scores_gather_kernel<<<dim3(L_SEQ / LB), 512, 0, stream>>>(Ewb, Eub, Wv, x, g);
}